// Round 11
// baseline (1760.005 us; speedup 1.0000x reference)
//
#include <hip/hip_runtime.h>
#include <hip/hip_bf16.h>
#include <math.h>

#define NV 20000
#define NE 320000
#define CSR_PAD 8
#define GRID 1280   // 5 blocks/CU on 256 CUs -- guaranteed co-resident (see launch_bounds)

typedef __attribute__((ext_vector_type(8))) short bf16x8;
typedef __attribute__((ext_vector_type(4))) float f32x4;
typedef __attribute__((ext_vector_type(2))) _Float16 h2;

static __device__ __forceinline__ ushort f2b(float f) {
  __hip_bfloat16 h = __float2bfloat16(f);
  return *reinterpret_cast<ushort*>(&h);
}
static __device__ __forceinline__ float b2f(ushort u) {
  union { ushort s[2]; float f; } c;
  c.s[0] = 0; c.s[1] = u;
  return c.f;
}
static __device__ __forceinline__ ushort f2h(float f) {
  _Float16 h = (_Float16)f;
  return *reinterpret_cast<ushort*>(&h);
}

// DPP wave-64 sum: 6 VALU adds; lane 63 holds total, broadcast via readlane.
static __device__ __forceinline__ float wave_sum64(float x) {
  x += __int_as_float(__builtin_amdgcn_update_dpp(0, __float_as_int(x), 0x111, 0xF, 0xF, true));
  x += __int_as_float(__builtin_amdgcn_update_dpp(0, __float_as_int(x), 0x112, 0xF, 0xF, true));
  x += __int_as_float(__builtin_amdgcn_update_dpp(0, __float_as_int(x), 0x114, 0xF, 0xF, true));
  x += __int_as_float(__builtin_amdgcn_update_dpp(0, __float_as_int(x), 0x118, 0xF, 0xF, true));
  x += __int_as_float(__builtin_amdgcn_update_dpp(0, __float_as_int(x), 0x142, 0xA, 0xF, true));
  x += __int_as_float(__builtin_amdgcn_update_dpp(0, __float_as_int(x), 0x143, 0xC, 0xF, true));
  return __int_as_float(__builtin_amdgcn_readlane(__float_as_int(x), 63));
}

// 16-channel dot: edge attrs as 8 packed f16 pairs vs pre-packed We pairs.
static __device__ __forceinline__ float dot16h(const uint4* __restrict__ E,
                                               const h2* __restrict__ Wch) {
#if __has_builtin(__builtin_amdgcn_fdot2)
  const h2* e = (const h2*)E;
  float s = 0.f;
#pragma unroll
  for (int j = 0; j < 8; ++j) s = __builtin_amdgcn_fdot2(e[j], Wch[j], s, false);
  return s;
#else
  const unsigned* u = (const unsigned*)E;
  float s = 0.f;
#pragma unroll
  for (int j = 0; j < 8; ++j) {
    union { unsigned v; h2 h; } cv; cv.v = u[j];
    s = fmaf((float)cv.h[0], (float)Wch[j][0], s);
    s = fmaf((float)cv.h[1], (float)Wch[j][1], s);
  }
  return s;
#endif
}

union SharedU {
  struct { ushort As[128][40]; ushort Bs[64][40]; } g;  // 15360 B (max member)
  float4 red4[256];
  struct { int wsum4[4]; int carry; } sc;
  struct { float r1s[4]; float r2s[4]; } ag;
};

struct CJob { const float* src; ushort* dst; int K, M; };

struct MegaArgs {
  const float *x, *Wp, *bp, *gp, *bep;
  const int* ei[3];
  const float* ea[3];
  CJob jobs[9];
  const float *bl[3], *br[3], *bsk[3];
  const float *We[3], *att[3], *bc[3], *gw[3], *be[3];
  const ushort* Wcat[3];
  ushort *B1, *B2; float* B3;
  ushort* h[3];
  float* easum; int* counts; int* cursor;
  unsigned* csr[3]; ushort* eab[3];
  int* bar;      // bar[0..8] phase counters, bar[16] generation (separate line)
  float* outf;
};

// ---- software grid barrier: all GRID blocks co-resident (launch_bounds-guaranteed).
// Release fence writes back this XCD's L2 (every XCD hosts blocks -> all flushed);
// acquire fence invalidates stale lines after the generation flips. [G16]
static __device__ __forceinline__ void gridbar(int* bar, int phase) {
  __syncthreads();
  if (threadIdx.x == 0) {
    __builtin_amdgcn_fence(__ATOMIC_RELEASE, "agent");
    int* gen = bar + 16;
    int arrived = __hip_atomic_fetch_add(&bar[phase], 1, __ATOMIC_RELAXED,
                                         __HIP_MEMORY_SCOPE_AGENT);
    if (arrived == GRID - 1) {
      __hip_atomic_store(gen, phase + 1, __ATOMIC_RELEASE, __HIP_MEMORY_SCOPE_AGENT);
    } else {
      while (__hip_atomic_load(gen, __ATOMIC_RELAXED, __HIP_MEMORY_SCOPE_AGENT) <= phase)
        __builtin_amdgcn_s_sleep(2);
    }
    __builtin_amdgcn_fence(__ATOMIC_ACQUIRE, "agent");
  }
  __syncthreads();
}

// ---------------- gemm phase: [xl | xr | res] = A @ [Wl|Wr|Wsk] + bias (grid-stride tiles) ----------------
static __device__ void gemm_phase(SharedU& sh, const ushort* __restrict__ A,
                                  const ushort* __restrict__ WT,
                                  const float* __restrict__ b0, const float* __restrict__ b1,
                                  const float* __restrict__ b2,
                                  ushort* __restrict__ O0, ushort* __restrict__ O1,
                                  float* __restrict__ O2,
                                  int K, int M1, int M2, int Mtot) {
  const int t = threadIdx.x, wave = t >> 6, lane = t & 63;
  const int m_ = lane & 15, q = lane >> 4;
  const int mcols = Mtot >> 6, nrows = (NV + 127) >> 7;
  const int ntiles = mcols * nrows;
  const int ar = t >> 1, ac = (t & 1) * 16;
  const int br = t >> 2, bcol = (t & 3) * 8;

  for (int tile = blockIdx.x; tile < ntiles; tile += GRID) {
    const int col0 = (tile % mcols) * 64, row0 = (tile / mcols) * 128;
    f32x4 acc[2][4];
#pragma unroll
    for (int i = 0; i < 2; ++i)
#pragma unroll
      for (int j = 0; j < 4; ++j) acc[i][j] = (f32x4){0.f, 0.f, 0.f, 0.f};

    const ushort* Ap = A + (size_t)(row0 + ar) * K + ac;
    const ushort* Bp = WT + (size_t)(col0 + br) * K + bcol;
    const bool a_ok = (row0 + ar) < NV;

    for (int k0 = 0; k0 < K; k0 += 32) {
      uint4 av0 = make_uint4(0, 0, 0, 0), av1 = make_uint4(0, 0, 0, 0);
      if (a_ok) { av0 = *(const uint4*)(Ap + k0); av1 = *(const uint4*)(Ap + k0 + 8); }
      uint4 bv = *(const uint4*)(Bp + k0);
      *(uint4*)&sh.g.As[ar][ac] = av0;
      *(uint4*)&sh.g.As[ar][ac + 8] = av1;
      *(uint4*)&sh.g.Bs[br][bcol] = bv;
      __syncthreads();
      bf16x8 a0 = *(const bf16x8*)&sh.g.As[wave * 32 + m_][q * 8];
      bf16x8 a1 = *(const bf16x8*)&sh.g.As[wave * 32 + 16 + m_][q * 8];
#pragma unroll
      for (int cf = 0; cf < 4; ++cf) {
        bf16x8 b = *(const bf16x8*)&sh.g.Bs[cf * 16 + m_][q * 8];
        acc[0][cf] = __builtin_amdgcn_mfma_f32_16x16x32_bf16(a0, b, acc[0][cf], 0, 0, 0);
        acc[1][cf] = __builtin_amdgcn_mfma_f32_16x16x32_bf16(a1, b, acc[1][cf], 0, 0, 0);
      }
      __syncthreads();
    }

    const float* bias; int base, mode, Wd;
    if (col0 < M1)      { bias = b0; base = 0;  mode = 0; Wd = M1; }
    else if (col0 < M2) { bias = b1; base = M1; mode = 1; Wd = M2 - M1; }
    else                { bias = b2; base = M2; mode = 2; Wd = Mtot - M2; }

#pragma unroll
    for (int rf = 0; rf < 2; ++rf) {
#pragma unroll
      for (int cf = 0; cf < 4; ++cf) {
        int col = col0 + cf * 16 + m_ - base;
        float bb = bias[col];
#pragma unroll
        for (int r = 0; r < 4; ++r) {
          int row = row0 + wave * 32 + rf * 16 + q * 4 + r;
          if (row < NV) {
            float v = acc[rf][cf][r] + bb;
            if (mode == 0)      O0[(size_t)row * Wd + col] = f2b(v);
            else if (mode == 1) O1[(size_t)row * Wd + col] = f2b(v);
            else                O2[(size_t)row * Wd + col] = v;
          }
        }
      }
    }
  }
}

// ---------------- agg phase: score + softmax + aggregate + LN + gelu + res ----------------
template <int H>
static __device__ void agg_phase(SharedU& sh, const ushort* __restrict__ eab,
                                 const float* __restrict__ easum,
                                 const float* __restrict__ We,
                                 const ushort* __restrict__ xl, const ushort* __restrict__ xr,
                                 const float* __restrict__ att, const float* __restrict__ bc,
                                 const float* __restrict__ g, const float* __restrict__ be,
                                 const float* __restrict__ res,
                                 const int* __restrict__ offs, const unsigned* __restrict__ csr,
                                 float* __restrict__ houtf, ushort* __restrict__ houtb) {
  const int HC = H * 64;
  const int t = threadIdx.x, lane = t & 63, wave = t >> 6;
  const int c = (H == 1) ? lane : t;

  const float att_t = att[c] * 1.4426950408889634f;  // fold log2(e)
  float eself0 = 0.f;
  h2 Wch[8];
#pragma unroll
  for (int j = 0; j < 8; ++j) {
    float w0 = We[(2 * j) * HC + c], w1 = We[(2 * j + 1) * HC + c];
    eself0 = fmaf(easum[2 * j], w0, eself0);
    eself0 = fmaf(easum[2 * j + 1], w1, eself0);
    Wch[j] = (h2){(_Float16)w0, (_Float16)w1};
  }
  const float eself = eself0 * (1.0f / (float)NE);

  const int node_step = (H == 1) ? GRID * 4 : GRID;
  const int n0 = (H == 1) ? blockIdx.x * 4 + wave : blockIdx.x;

  for (int n = n0; n < NV + ((H == 1) ? 3 : 0); n += node_step) {
    const bool active = n < NV;
    float out = 0.f;
    if (active) {
      const float xr_t = b2f(xr[(size_t)n * HC + c]);
      const float xln = b2f(xl[(size_t)n * HC + c]);
      float vs = xln + xr_t + eself;
      vs = vs > 0.f ? vs : 0.2f * vs;
      const float wself = exp2f(wave_sum64(vs * att_t));
      float acc = wself * xln, denom = wself;

      const int beg = __builtin_amdgcn_readfirstlane(offs[n]);
      const int end = __builtin_amdgcn_readfirstlane(offs[n + 1]);

      unsigned P[4];
      uint4 EA[4][2];
      float XL[4];
#pragma unroll
      for (int k = 0; k < 4; ++k) {
        P[k] = csr[beg + k];
        const uint4* ep = (const uint4*)(eab + (size_t)(beg + k) * 16);
        EA[k][0] = ep[0]; EA[k][1] = ep[1];
      }
#pragma unroll
      for (int k = 0; k < 4; ++k)
        XL[k] = b2f(xl[__builtin_amdgcn_readfirstlane(P[k]) + c]);

      for (int idx = beg; idx < end; idx += 4) {
        unsigned Q[4];
        uint4 EB[4][2];
        float XLN[4];
#pragma unroll
        for (int k = 0; k < 4; ++k) Q[k] = csr[idx + 4 + k];
#pragma unroll
        for (int k = 0; k < 4; ++k) {
          const uint4* ep = (const uint4*)(eab + (size_t)(idx + 4 + k) * 16);
          EB[k][0] = ep[0]; EB[k][1] = ep[1];
        }
#pragma unroll
        for (int k = 0; k < 4; ++k)
          XLN[k] = b2f(xl[__builtin_amdgcn_readfirstlane(Q[k]) + c]);

        float wv[4];
#pragma unroll
        for (int k = 0; k < 4; ++k) {
          float ee = dot16h(EA[k], Wch);
          float v = XL[k] + xr_t + ee;
          v = v > 0.f ? v : 0.2f * v;  // leaky_relu(0.2)
          float S = wave_sum64(v * att_t);
          wv[k] = (idx + k < end) ? exp2f(S) : 0.f;
        }
#pragma unroll
        for (int k = 0; k < 4; ++k) { acc = fmaf(wv[k], XL[k], acc); denom += wv[k]; }
#pragma unroll
        for (int k = 0; k < 4; ++k) {
          P[k] = Q[k]; EA[k][0] = EB[k][0]; EA[k][1] = EB[k][1]; XL[k] = XLN[k];
        }
      }
      out = acc / (denom + 1e-16f) + bc[c];
    }

    // LayerNorm across HC channels (H=4 needs cross-wave; uniform trip count per block)
    float s1 = wave_sum64(out), s2 = wave_sum64(out * out);
    if (H > 1) {
      if (lane == 0) { sh.ag.r1s[wave] = s1; sh.ag.r2s[wave] = s2; }
      __syncthreads();
      s1 = 0.f; s2 = 0.f;
#pragma unroll
      for (int j = 0; j < H; ++j) { s1 += sh.ag.r1s[j]; s2 += sh.ag.r2s[j]; }
    }
    if (active) {
      float mean = s1 / (float)HC;
      float var  = s2 / (float)HC - mean * mean;
      float y = (out - mean) * rsqrtf(var + 1e-5f) * g[c] + be[c];
      float gel = 0.5f * y * (1.0f + erff(y * 0.70710678118654752f));
      float o = gel + res[(size_t)n * HC + c];
      if (houtf) houtf[(size_t)n * HC + c] = o;
      if (houtb) houtb[(size_t)n * HC + c] = f2b(o);
    }
    if (H > 1) __syncthreads();  // protect r1s/r2s before next node
  }
}

// ---------------- THE mega kernel: all phases, software grid barriers ----------------
__global__ __launch_bounds__(256, 5) void mega_kernel(MegaArgs a) {
  __shared__ SharedU sh;
  const int t = threadIdx.x, bid = blockIdx.x;
  const int gid = bid * 256 + t;
  const int IC[3] = {64, 256, 256}, HCA[3] = {256, 256, 64}, OCA[3] = {256, 256, 64};

  // ---- P0: zero counts + easum ----
  for (int i = gid; i < 3 * (NV + 1); i += GRID * 256) a.counts[i] = 0;
  if (gid < 48) a.easum[gid] = 0.f;
  gridbar(a.bar, 0);

  // ---- P1: ea colsum (blocks<256) + dst hist + weight casts + proj ----
  if (bid < 256) {
    for (int l = 0; l < 3; ++l) {
      const float4* ea4 = (const float4*)a.ea[l];
      const int cg = t & 3;
      int r = bid * 64 + (t >> 2);
      float4 s = make_float4(0.f, 0.f, 0.f, 0.f);
      for (; r < NE; r += 256 * 64) {
        float4 v = ea4[(size_t)r * 4 + cg];
        s.x += v.x; s.y += v.y; s.z += v.z; s.w += v.w;
      }
      sh.red4[t] = s;
      __syncthreads();
      if (t < 4) {
        float4 tot = make_float4(0.f, 0.f, 0.f, 0.f);
        for (int j = t; j < 256; j += 4) {
          float4 v = sh.red4[j];
          tot.x += v.x; tot.y += v.y; tot.z += v.z; tot.w += v.w;
        }
        atomicAdd(&a.easum[l * 16 + t * 4 + 0], tot.x);
        atomicAdd(&a.easum[l * 16 + t * 4 + 1], tot.y);
        atomicAdd(&a.easum[l * 16 + t * 4 + 2], tot.z);
        atomicAdd(&a.easum[l * 16 + t * 4 + 3], tot.w);
      }
      __syncthreads();
    }
  }
  for (int l = 0; l < 3; ++l)
    for (int i = gid; i < NE; i += GRID * 256)
      atomicAdd(&a.counts[l * (NV + 1) + a.ei[l][NE + i]], 1);
#pragma unroll
  for (int j = 0; j < 9; ++j) {
    CJob jb = a.jobs[j];
    const int total = jb.M * jb.K;
    for (int i = gid; i < total; i += GRID * 256) {
      int m = i / jb.K, k = i - m * jb.K;
      jb.dst[i] = f2b(jb.src[(size_t)k * jb.M + m]);
    }
  }
  {
    int wid = t >> 6, lane = t & 63;
    for (int row = bid * 4 + wid; row < NV; row += GRID * 4) {
      float xv = a.x[(size_t)row * 64 + lane];
      float acc = a.bp[lane];
#pragma unroll
      for (int k = 0; k < 64; ++k) {
        float v = __shfl(xv, k, 64);
        acc = fmaf(v, a.Wp[k * 64 + lane], acc);
      }
      float s1 = wave_sum64(acc), s2 = wave_sum64(acc * acc);
      float mean = s1 * (1.0f / 64.0f);
      float var  = s2 * (1.0f / 64.0f) - mean * mean;
      float yv = (acc - mean) * rsqrtf(var + 1e-5f) * a.gp[lane] + a.bep[lane];
      float gel = 0.5f * yv * (1.0f + erff(yv * 0.70710678118654752f));
      a.h[0][(size_t)row * 64 + lane] = f2b(gel);
    }
  }
  gridbar(a.bar, 1);

  // ---- P2: scan (blocks 0..2, one layer each; 256 thr, 8 chunks of 2560) ----
  if (bid < 3) {
    int* counts = a.counts + bid * (NV + 1);
    int* cursor = a.cursor + bid * NV;
    const int lane = t & 63, wid = t >> 6;
    if (t == 0) sh.sc.carry = 0;
    __syncthreads();
    for (int base = 0; base < NV; base += 2560) {
      int v[10], tot = 0;
#pragma unroll
      for (int j = 0; j < 10; ++j) {
        int i = base + t * 10 + j;
        v[j] = (i < NV) ? counts[i] : 0;
        tot += v[j];
      }
      int x = tot;
#pragma unroll
      for (int o = 1; o < 64; o <<= 1) {
        int y = __shfl_up(x, o, 64);
        if (lane >= o) x += y;
      }
      if (lane == 63) sh.sc.wsum4[wid] = x;
      __syncthreads();
      int wpre = 0;
      for (int j = 0; j < wid; ++j) wpre += sh.sc.wsum4[j];
      int carry = sh.sc.carry;
      int run = carry + wpre + (x - tot);
#pragma unroll
      for (int j = 0; j < 10; ++j) {
        int i = base + t * 10 + j;
        if (i < NV) { counts[i] = run; cursor[i] = run; }
        run += v[j];
      }
      __syncthreads();
      if (t == 255) sh.sc.carry = carry + wpre + x;
      __syncthreads();
    }
    if (t == 0) counts[NV] = sh.sc.carry;
  }
  gridbar(a.bar, 2);

  // ---- P3: scatter src-offset CSR + reorder ea -> f16 CSR order ----
  for (int l = 0; l < 3; ++l) {
    const int HCl = HCA[l];
    for (int i = gid; i < NE + CSR_PAD; i += GRID * 256) {
      if (i >= NE) {
        a.csr[l][i] = 0u;
        uint4 z = make_uint4(0, 0, 0, 0);
        *(uint4*)(a.eab[l] + (size_t)i * 16) = z;
        *(uint4*)(a.eab[l] + (size_t)i * 16 + 8) = z;
        continue;
      }
      int dst = a.ei[l][NE + i], src = a.ei[l][i];
      int pos = atomicAdd(&a.cursor[l * 0 + 0 * 0 + 0] + (size_t)l * NV + dst, 1);
      a.csr[l][pos] = (unsigned)(src * HCl);
      const float4* er = (const float4*)(a.ea[l] + (size_t)i * 16);
      float4 q0 = er[0], q1 = er[1], q2 = er[2], q3 = er[3];
      uint4 w0, w1;
      w0.x = (unsigned)f2h(q0.x) | ((unsigned)f2h(q0.y) << 16);
      w0.y = (unsigned)f2h(q0.z) | ((unsigned)f2h(q0.w) << 16);
      w0.z = (unsigned)f2h(q1.x) | ((unsigned)f2h(q1.y) << 16);
      w0.w = (unsigned)f2h(q1.z) | ((unsigned)f2h(q1.w) << 16);
      w1.x = (unsigned)f2h(q2.x) | ((unsigned)f2h(q2.y) << 16);
      w1.y = (unsigned)f2h(q2.z) | ((unsigned)f2h(q2.w) << 16);
      w1.z = (unsigned)f2h(q3.x) | ((unsigned)f2h(q3.y) << 16);
      w1.w = (unsigned)f2h(q3.z) | ((unsigned)f2h(q3.w) << 16);
      *(uint4*)(a.eab[l] + (size_t)pos * 16) = w0;
      *(uint4*)(a.eab[l] + (size_t)pos * 16 + 8) = w1;
    }
  }
  gridbar(a.bar, 3);

  // ---- per-layer: gemm -> barrier -> agg -> barrier ----
  for (int l = 0; l < 3; ++l) {
    const int K = IC[l], HCl = HCA[l], OCl = OCA[l];
    gemm_phase(sh, a.h[l], a.Wcat[l], a.bl[l], a.br[l], a.bsk[l],
               a.B1, a.B2, a.B3, K, HCl, 2 * HCl, 2 * HCl + OCl);
    gridbar(a.bar, 4 + 2 * l);
    const int* offs = a.counts + l * (NV + 1);
    if (l < 2) {
      agg_phase<4>(sh, a.eab[l], a.easum + l * 16, a.We[l], a.B1, a.B2,
                   a.att[l], a.bc[l], a.gw[l], a.be[l], a.B3,
                   offs, a.csr[l], nullptr, a.h[l + 1]);
      gridbar(a.bar, 5 + 2 * l);
    } else {
      agg_phase<1>(sh, a.eab[l], a.easum + l * 16, a.We[l], a.B1, a.B2,
                   a.att[l], a.bc[l], a.gw[l], a.be[l], a.B3,
                   offs, a.csr[l], a.outf, nullptr);
    }
  }
}

// ---------------- host launch ----------------
extern "C" void kernel_launch(void* const* d_in, const int* in_sizes, int n_in,
                              void* d_out, int out_size, void* d_ws, size_t ws_size,
                              hipStream_t stream)
{
  auto in = [&](int i) { return (const float*)d_in[i]; };
  // per-layer base 11 + 11*i: Wl, bl, Wr, br, We, att, bc, g, be, Wsk, bsk

  const int ic[3] = {64, 256, 256}, hc[3] = {256, 256, 64}, oc[3] = {256, 256, 64};
  const int CSRN = NE + CSR_PAD;

  // ---- workspace layout (~99 MB) ----
  char* w = (char*)d_ws;
  size_t off = 0;
  auto alloc = [&](size_t bytes) { void* p = w + off; off = (off + bytes + 511) & ~(size_t)511; return p; };
  MegaArgs a;
  a.B1 = (ushort*)alloc((size_t)NV * 256 * 2);
  a.B2 = (ushort*)alloc((size_t)NV * 256 * 2);
  a.B3 = (float*)alloc((size_t)NV * 256 * 4);
  a.h[0] = (ushort*)alloc((size_t)NV * 64 * 2);
  a.h[1] = (ushort*)alloc((size_t)NV * 256 * 2);
  a.h[2] = (ushort*)alloc((size_t)NV * 256 * 2);
  ushort* Wcat[3];
  for (int i = 0; i < 3; ++i) {
    Wcat[i] = (ushort*)alloc((size_t)(2 * hc[i] + oc[i]) * ic[i] * 2);
    a.Wcat[i] = Wcat[i];
  }
  a.easum  = (float*)alloc(3 * 64);
  a.counts = (int*)alloc((size_t)3 * (NV + 1) * 4);
  a.cursor = (int*)alloc((size_t)3 * NV * 4);
  for (int i = 0; i < 3; ++i) a.csr[i] = (unsigned*)alloc((size_t)CSRN * 4);
  for (int i = 0; i < 3; ++i) a.eab[i] = (ushort*)alloc((size_t)CSRN * 16 * 2);
  a.bar = (int*)alloc(128);

  a.x = in(0);
  a.Wp = in(7); a.bp = in(8); a.gp = in(9); a.bep = in(10);
  for (int i = 0; i < 3; ++i) {
    a.ei[i] = (const int*)d_in[1 + 2 * i];
    a.ea[i] = in(2 + 2 * i);
    a.jobs[i * 3 + 0] = {in(11 + 11 * i), Wcat[i],                             ic[i], hc[i]};
    a.jobs[i * 3 + 1] = {in(13 + 11 * i), Wcat[i] + (size_t)hc[i] * ic[i],     ic[i], hc[i]};
    a.jobs[i * 3 + 2] = {in(20 + 11 * i), Wcat[i] + (size_t)2 * hc[i] * ic[i], ic[i], oc[i]};
    a.bl[i]  = in(12 + 11 * i);
    a.br[i]  = in(14 + 11 * i);
    a.We[i]  = in(15 + 11 * i);
    a.att[i] = in(16 + 11 * i);
    a.bc[i]  = in(17 + 11 * i);
    a.gw[i]  = in(18 + 11 * i);
    a.be[i]  = in(19 + 11 * i);
    a.bsk[i] = in(21 + 11 * i);
  }
  a.outf = (float*)d_out;

  // node 1: zero the barrier state (counters + generation)
  hipMemsetAsync(a.bar, 0, 128, stream);
  // node 2: everything else
  mega_kernel<<<GRID, 256, 0, stream>>>(a);
}

// Round 12
// 834.996 us; speedup vs baseline: 2.1078x; 2.1078x over previous
//
#include <hip/hip_runtime.h>
#include <hip/hip_bf16.h>
#include <math.h>

#define NV 20000
#define NE 320000
#define CSR_PAD 8
#define GRID1 1280          // 5 blocks/CU -- co-residency proven in r11
#define BAR_READY 24
#define BAR_MAGIC 0x1357A5A5

typedef __attribute__((ext_vector_type(8))) short bf16x8;
typedef __attribute__((ext_vector_type(4))) float f32x4;
typedef __attribute__((ext_vector_type(2))) _Float16 h2;

static __device__ __forceinline__ ushort f2b(float f) {
  __hip_bfloat16 h = __float2bfloat16(f);
  return *reinterpret_cast<ushort*>(&h);
}
static __device__ __forceinline__ float b2f(ushort u) {
  union { ushort s[2]; float f; } c;
  c.s[0] = 0; c.s[1] = u;
  return c.f;
}
static __device__ __forceinline__ ushort f2h(float f) {
  _Float16 h = (_Float16)f;
  return *reinterpret_cast<ushort*>(&h);
}

// DPP wave-64 sum: 6 VALU adds; lane 63 holds total, broadcast via readlane.
static __device__ __forceinline__ float wave_sum64(float x) {
  x += __int_as_float(__builtin_amdgcn_update_dpp(0, __float_as_int(x), 0x111, 0xF, 0xF, true));
  x += __int_as_float(__builtin_amdgcn_update_dpp(0, __float_as_int(x), 0x112, 0xF, 0xF, true));
  x += __int_as_float(__builtin_amdgcn_update_dpp(0, __float_as_int(x), 0x114, 0xF, 0xF, true));
  x += __int_as_float(__builtin_amdgcn_update_dpp(0, __float_as_int(x), 0x118, 0xF, 0xF, true));
  x += __int_as_float(__builtin_amdgcn_update_dpp(0, __float_as_int(x), 0x142, 0xA, 0xF, true));
  x += __int_as_float(__builtin_amdgcn_update_dpp(0, __float_as_int(x), 0x143, 0xC, 0xF, true));
  return __int_as_float(__builtin_amdgcn_readlane(__float_as_int(x), 63));
}

// 16-channel dot: edge attrs as 8 packed f16 pairs vs pre-packed We pairs.
static __device__ __forceinline__ float dot16h(const uint4* __restrict__ E,
                                               const h2* __restrict__ Wch) {
#if __has_builtin(__builtin_amdgcn_fdot2)
  const h2* e = (const h2*)E;
  float s = 0.f;
#pragma unroll
  for (int j = 0; j < 8; ++j) s = __builtin_amdgcn_fdot2(e[j], Wch[j], s, false);
  return s;
#else
  const unsigned* u = (const unsigned*)E;
  float s = 0.f;
#pragma unroll
  for (int j = 0; j < 8; ++j) {
    union { unsigned v; h2 h; } cv; cv.v = u[j];
    s = fmaf((float)cv.h[0], (float)Wch[j][0], s);
    s = fmaf((float)cv.h[1], (float)Wch[j][1], s);
  }
  return s;
#endif
}

// ---- software grid barrier (validated r11): all GRID1 blocks co-resident.
// Release fence drains this XCD's L2; acquire invalidates after the flip. [G16]
static __device__ __forceinline__ void gridbar(int* bar, int phase) {
  __syncthreads();
  if (threadIdx.x == 0) {
    __builtin_amdgcn_fence(__ATOMIC_RELEASE, "agent");
    int* gen = bar + 16;
    int arrived = __hip_atomic_fetch_add(&bar[phase], 1, __ATOMIC_RELAXED,
                                         __HIP_MEMORY_SCOPE_AGENT);
    if (arrived == GRID1 - 1) {
      __hip_atomic_store(gen, phase + 1, __ATOMIC_RELEASE, __HIP_MEMORY_SCOPE_AGENT);
    } else {
      while (__hip_atomic_load(gen, __ATOMIC_RELAXED, __HIP_MEMORY_SCOPE_AGENT) <= phase)
        __builtin_amdgcn_s_sleep(2);
    }
    __builtin_amdgcn_fence(__ATOMIC_ACQUIRE, "agent");
  }
  __syncthreads();
}

struct CJob { const float* src; ushort* dst; int K, M; };

struct PrepArgs {
  const float *x, *Wp, *bp, *gp, *bep;
  const int* ei[3];
  const float* ea[3];
  CJob jobs[9];
  ushort* h0;
  float* easum; int* counts; int* cursor;
  unsigned* csr[3]; ushort* eab[3];
  int* bar;
};

// ---------------- ONE preprocessing kernel: zero -> (colsum,hist,casts,proj) -> scan -> scatter ----------------
// No MFMA phase => low VGPR => no spills (the r11 mega-kernel failure mode).
__global__ __launch_bounds__(256, 5) void prepcsr_kernel(PrepArgs a) {
  __shared__ float4 red4[256];
  __shared__ int wsum4[4];
  __shared__ int carry_s;
  const int t = threadIdx.x, bid = blockIdx.x;
  const int gid = bid * 256 + t;
  const int HCA[3] = {256, 256, 64};

  // barrier self-init: block 0 zeroes state, release-publishes ready flag.
  if (bid == 0 && t == 0) {
    for (int i = 0; i < 24; ++i) a.bar[i] = 0;
    __hip_atomic_store(&a.bar[BAR_READY], BAR_MAGIC, __ATOMIC_RELEASE,
                       __HIP_MEMORY_SCOPE_AGENT);
  }

  // ---- P0: zero counts + easum (overlapped with bar init) ----
  for (int i = gid; i < 3 * (NV + 1); i += GRID1 * 256) a.counts[i] = 0;
  if (gid < 48) a.easum[gid] = 0.f;
  if (t == 0) {  // wait for barrier state to be initialized
    while (__hip_atomic_load(&a.bar[BAR_READY], __ATOMIC_ACQUIRE,
                             __HIP_MEMORY_SCOPE_AGENT) != BAR_MAGIC)
      __builtin_amdgcn_s_sleep(2);
  }
  gridbar(a.bar, 0);

  // ---- P1: ea colsum (blocks<256) + dst hist + weight casts + proj ----
  if (bid < 256) {
    for (int l = 0; l < 3; ++l) {
      const float4* ea4 = (const float4*)a.ea[l];
      const int cg = t & 3;
      int r = bid * 64 + (t >> 2);
      float4 s = make_float4(0.f, 0.f, 0.f, 0.f);
      for (; r < NE; r += 256 * 64) {
        float4 v = ea4[(size_t)r * 4 + cg];
        s.x += v.x; s.y += v.y; s.z += v.z; s.w += v.w;
      }
      red4[t] = s;
      __syncthreads();
      if (t < 4) {
        float4 tot = make_float4(0.f, 0.f, 0.f, 0.f);
        for (int j = t; j < 256; j += 4) {
          float4 v = red4[j];
          tot.x += v.x; tot.y += v.y; tot.z += v.z; tot.w += v.w;
        }
        atomicAdd(&a.easum[l * 16 + t * 4 + 0], tot.x);
        atomicAdd(&a.easum[l * 16 + t * 4 + 1], tot.y);
        atomicAdd(&a.easum[l * 16 + t * 4 + 2], tot.z);
        atomicAdd(&a.easum[l * 16 + t * 4 + 3], tot.w);
      }
      __syncthreads();
    }
  }
  for (int l = 0; l < 3; ++l)
    for (int i = gid; i < NE; i += GRID1 * 256)
      atomicAdd(&a.counts[l * (NV + 1) + a.ei[l][NE + i]], 1);
#pragma unroll
  for (int j = 0; j < 9; ++j) {
    CJob jb = a.jobs[j];
    const int total = jb.M * jb.K;
    for (int i = gid; i < total; i += GRID1 * 256) {
      int m = i / jb.K, k = i - m * jb.K;
      jb.dst[i] = f2b(jb.src[(size_t)k * jb.M + m]);
    }
  }
  {
    int wid = t >> 6, lane = t & 63;
    for (int row = bid * 4 + wid; row < NV; row += GRID1 * 4) {
      float xv = a.x[(size_t)row * 64 + lane];
      float acc = a.bp[lane];
#pragma unroll
      for (int k = 0; k < 64; ++k) {
        float v = __shfl(xv, k, 64);
        acc = fmaf(v, a.Wp[k * 64 + lane], acc);
      }
      float s1 = wave_sum64(acc), s2 = wave_sum64(acc * acc);
      float mean = s1 * (1.0f / 64.0f);
      float var  = s2 * (1.0f / 64.0f) - mean * mean;
      float yv = (acc - mean) * rsqrtf(var + 1e-5f) * a.gp[lane] + a.bep[lane];
      float gel = 0.5f * yv * (1.0f + erff(yv * 0.70710678118654752f));
      a.h0[(size_t)row * 64 + lane] = f2b(gel);
    }
  }
  gridbar(a.bar, 1);

  // ---- P2: exclusive scan (blocks 0..2, one layer each; validated in r11) ----
  if (bid < 3) {
    int* counts = a.counts + bid * (NV + 1);
    int* cursor = a.cursor + bid * NV;
    const int lane = t & 63, wid = t >> 6;
    if (t == 0) carry_s = 0;
    __syncthreads();
    for (int base = 0; base < NV; base += 2560) {
      int v[10], tot = 0;
#pragma unroll
      for (int j = 0; j < 10; ++j) {
        int i = base + t * 10 + j;
        v[j] = (i < NV) ? counts[i] : 0;
        tot += v[j];
      }
      int x = tot;
#pragma unroll
      for (int o = 1; o < 64; o <<= 1) {
        int y = __shfl_up(x, o, 64);
        if (lane >= o) x += y;
      }
      if (lane == 63) wsum4[wid] = x;
      __syncthreads();
      int wpre = 0;
      for (int j = 0; j < wid; ++j) wpre += wsum4[j];
      int carry = carry_s;
      int run = carry + wpre + (x - tot);
#pragma unroll
      for (int j = 0; j < 10; ++j) {
        int i = base + t * 10 + j;
        if (i < NV) { counts[i] = run; cursor[i] = run; }
        run += v[j];
      }
      __syncthreads();
      if (t == 255) carry_s = carry + wpre + x;
      __syncthreads();
    }
    if (t == 0) counts[NV] = carry_s;
  }
  gridbar(a.bar, 2);

  // ---- P3: scatter src-offset CSR + reorder ea -> f16 CSR order ----
  for (int l = 0; l < 3; ++l) {
    const int HCl = HCA[l];
    int* cur = a.cursor + l * NV;
    for (int i = gid; i < NE + CSR_PAD; i += GRID1 * 256) {
      if (i >= NE) {
        a.csr[l][i] = 0u;
        uint4 z = make_uint4(0, 0, 0, 0);
        *(uint4*)(a.eab[l] + (size_t)i * 16) = z;
        *(uint4*)(a.eab[l] + (size_t)i * 16 + 8) = z;
        continue;
      }
      int dst = a.ei[l][NE + i], src = a.ei[l][i];
      int pos = atomicAdd(&cur[dst], 1);
      a.csr[l][pos] = (unsigned)(src * HCl);
      const float4* er = (const float4*)(a.ea[l] + (size_t)i * 16);
      float4 q0 = er[0], q1 = er[1], q2 = er[2], q3 = er[3];
      uint4 w0, w1;
      w0.x = (unsigned)f2h(q0.x) | ((unsigned)f2h(q0.y) << 16);
      w0.y = (unsigned)f2h(q0.z) | ((unsigned)f2h(q0.w) << 16);
      w0.z = (unsigned)f2h(q1.x) | ((unsigned)f2h(q1.y) << 16);
      w0.w = (unsigned)f2h(q1.z) | ((unsigned)f2h(q1.w) << 16);
      w1.x = (unsigned)f2h(q2.x) | ((unsigned)f2h(q2.y) << 16);
      w1.y = (unsigned)f2h(q2.z) | ((unsigned)f2h(q2.w) << 16);
      w1.z = (unsigned)f2h(q3.x) | ((unsigned)f2h(q3.y) << 16);
      w1.w = (unsigned)f2h(q3.z) | ((unsigned)f2h(q3.w) << 16);
      *(uint4*)(a.eab[l] + (size_t)pos * 16) = w0;
      *(uint4*)(a.eab[l] + (size_t)pos * 16 + 8) = w1;
    }
  }
}

// ---------------- fused per-layer GEMM: [xl | xr | res] = A @ [Wl|Wr|Wsk] + bias ----------------
// Standalone dispatch => own VGPR budget => no spills (r11 lesson).
__global__ __launch_bounds__(256) void gemm_fused(
    const ushort* __restrict__ A, const ushort* __restrict__ WT,
    const float* __restrict__ b0, const float* __restrict__ b1,
    const float* __restrict__ b2,
    ushort* __restrict__ O0, ushort* __restrict__ O1, float* __restrict__ O2,
    int N, int K, int M1, int M2, int Mtot)
{
  __shared__ ushort As[128][40];
  __shared__ ushort Bs[64][40];
  const int t = threadIdx.x, wave = t >> 6, lane = t & 63;
  const int row0 = blockIdx.y * 128, col0 = blockIdx.x * 64;
  const int m_ = lane & 15, q = lane >> 4;
  f32x4 acc[2][4];
#pragma unroll
  for (int i = 0; i < 2; ++i)
#pragma unroll
    for (int j = 0; j < 4; ++j) acc[i][j] = (f32x4){0.f, 0.f, 0.f, 0.f};

  const int ar = t >> 1, ac = (t & 1) * 16;
  const int br = t >> 2, bcol = (t & 3) * 8;
  const ushort* Ap = A + (size_t)(row0 + ar) * K + ac;
  const ushort* Bp = WT + (size_t)(col0 + br) * K + bcol;
  const bool a_ok = (row0 + ar) < N;

  for (int k0 = 0; k0 < K; k0 += 32) {
    uint4 av0 = make_uint4(0, 0, 0, 0), av1 = make_uint4(0, 0, 0, 0);
    if (a_ok) { av0 = *(const uint4*)(Ap + k0); av1 = *(const uint4*)(Ap + k0 + 8); }
    uint4 bv = *(const uint4*)(Bp + k0);
    *(uint4*)&As[ar][ac] = av0;
    *(uint4*)&As[ar][ac + 8] = av1;
    *(uint4*)&Bs[br][bcol] = bv;
    __syncthreads();
    bf16x8 a0 = *(const bf16x8*)&As[wave * 32 + m_][q * 8];
    bf16x8 a1 = *(const bf16x8*)&As[wave * 32 + 16 + m_][q * 8];
#pragma unroll
    for (int cf = 0; cf < 4; ++cf) {
      bf16x8 b = *(const bf16x8*)&Bs[cf * 16 + m_][q * 8];
      acc[0][cf] = __builtin_amdgcn_mfma_f32_16x16x32_bf16(a0, b, acc[0][cf], 0, 0, 0);
      acc[1][cf] = __builtin_amdgcn_mfma_f32_16x16x32_bf16(a1, b, acc[1][cf], 0, 0, 0);
    }
    __syncthreads();
  }

  const float* bias; int base, mode, Wd;
  if (col0 < M1)      { bias = b0; base = 0;  mode = 0; Wd = M1; }
  else if (col0 < M2) { bias = b1; base = M1; mode = 1; Wd = M2 - M1; }
  else                { bias = b2; base = M2; mode = 2; Wd = Mtot - M2; }

#pragma unroll
  for (int rf = 0; rf < 2; ++rf) {
#pragma unroll
    for (int cf = 0; cf < 4; ++cf) {
      int col = col0 + cf * 16 + m_ - base;
      float bb = bias[col];
#pragma unroll
      for (int r = 0; r < 4; ++r) {
        int row = row0 + wave * 32 + rf * 16 + q * 4 + r;
        if (row < N) {
          float v = acc[rf][cf][r] + bb;
          if (mode == 0)      O0[(size_t)row * Wd + col] = f2b(v);
          else if (mode == 1) O1[(size_t)row * Wd + col] = f2b(v);
          else                O2[(size_t)row * Wd + col] = v;
        }
      }
    }
  }
}

// ---------------- fused GATv2: score + softmax + aggregate + LN + gelu + res ----------------
template <int H>
__global__ __launch_bounds__(256, 4) void fused_agg_kernel(
    const ushort* __restrict__ eab, const float* __restrict__ easum,
    const float* __restrict__ We,
    const ushort* __restrict__ xl, const ushort* __restrict__ xr,
    const float* __restrict__ att, const float* __restrict__ bc,
    const float* __restrict__ g, const float* __restrict__ be,
    const float* __restrict__ res,
    const int* __restrict__ offs, const unsigned* __restrict__ csr,
    float* __restrict__ houtf, ushort* __restrict__ houtb, int E)
{
  const int HC = H * 64;
  const int t = threadIdx.x, lane = t & 63, wave = t >> 6;
  const int n = (H == 1) ? blockIdx.x * 4 + wave : blockIdx.x;
  const int c = (H == 1) ? lane : t;

  const float xr_t = b2f(xr[(size_t)n * HC + c]);
  const float att_t = att[c] * 1.4426950408889634f;  // fold log2(e)
  float eself = 0.f;
  h2 Wch[8];
#pragma unroll
  for (int j = 0; j < 8; ++j) {
    float w0 = We[(2 * j) * HC + c], w1 = We[(2 * j + 1) * HC + c];
    eself = fmaf(easum[2 * j], w0, eself);
    eself = fmaf(easum[2 * j + 1], w1, eself);
    Wch[j] = (h2){(_Float16)w0, (_Float16)w1};
  }
  eself *= 1.0f / (float)E;

  // self-loop contribution (analytic)
  const float xln = b2f(xl[(size_t)n * HC + c]);
  float vs = xln + xr_t + eself;
  vs = vs > 0.f ? vs : 0.2f * vs;
  const float wself = exp2f(wave_sum64(vs * att_t));
  float acc = wself * xln, denom = wself;

  const int beg = __builtin_amdgcn_readfirstlane(offs[n]);
  const int end = __builtin_amdgcn_readfirstlane(offs[n + 1]);

  unsigned P[4];
  uint4 EA[4][2];
  float XL[4];
#pragma unroll
  for (int k = 0; k < 4; ++k) {
    P[k] = csr[beg + k];
    const uint4* ep = (const uint4*)(eab + (size_t)(beg + k) * 16);
    EA[k][0] = ep[0]; EA[k][1] = ep[1];
  }
#pragma unroll
  for (int k = 0; k < 4; ++k)
    XL[k] = b2f(xl[__builtin_amdgcn_readfirstlane(P[k]) + c]);

  for (int idx = beg; idx < end; idx += 4) {
    unsigned Q[4];
    uint4 EB[4][2];
    float XLN[4];
#pragma unroll
    for (int k = 0; k < 4; ++k) Q[k] = csr[idx + 4 + k];
#pragma unroll
    for (int k = 0; k < 4; ++k) {
      const uint4* ep = (const uint4*)(eab + (size_t)(idx + 4 + k) * 16);
      EB[k][0] = ep[0]; EB[k][1] = ep[1];
    }
#pragma unroll
    for (int k = 0; k < 4; ++k)
      XLN[k] = b2f(xl[__builtin_amdgcn_readfirstlane(Q[k]) + c]);

    float wv[4];
#pragma unroll
    for (int k = 0; k < 4; ++k) {
      float ee = dot16h(EA[k], Wch);
      float v = XL[k] + xr_t + ee;
      v = v > 0.f ? v : 0.2f * v;  // leaky_relu(0.2)
      float S = wave_sum64(v * att_t);
      wv[k] = (idx + k < end) ? exp2f(S) : 0.f;
    }
#pragma unroll
    for (int k = 0; k < 4; ++k) { acc = fmaf(wv[k], XL[k], acc); denom += wv[k]; }
#pragma unroll
    for (int k = 0; k < 4; ++k) {
      P[k] = Q[k]; EA[k][0] = EB[k][0]; EA[k][1] = EB[k][1]; XL[k] = XLN[k];
    }
  }

  float out = acc / (denom + 1e-16f) + bc[c];

  // LayerNorm across HC channels
  float s1 = wave_sum64(out), s2 = wave_sum64(out * out);
  if (H > 1) {
    __shared__ float r1s[4], r2s[4];
    if (lane == 0) { r1s[wave] = s1; r2s[wave] = s2; }
    __syncthreads();
    s1 = 0.f; s2 = 0.f;
#pragma unroll
    for (int j = 0; j < H; ++j) { s1 += r1s[j]; s2 += r2s[j]; }
  }
  float mean = s1 / (float)HC;
  float var  = s2 / (float)HC - mean * mean;
  float y = (out - mean) * rsqrtf(var + 1e-5f) * g[c] + be[c];
  float gel = 0.5f * y * (1.0f + erff(y * 0.70710678118654752f));
  float o = gel + res[(size_t)n * HC + c];
  if (houtf) houtf[(size_t)n * HC + c] = o;
  if (houtb) houtb[(size_t)n * HC + c] = f2b(o);
}

// ---------------- host launch ----------------
extern "C" void kernel_launch(void* const* d_in, const int* in_sizes, int n_in,
                              void* d_out, int out_size, void* d_ws, size_t ws_size,
                              hipStream_t stream)
{
  auto in = [&](int i) { return (const float*)d_in[i]; };
  // per-layer base 11 + 11*i: Wl, bl, Wr, br, We, att, bc, g, be, Wsk, bsk

  const int ic[3] = {64, 256, 256}, hc[3] = {256, 256, 64}, oc[3] = {256, 256, 64};
  const int CSRN = NE + CSR_PAD;

  // ---- workspace layout (~100 MB) ----
  char* w = (char*)d_ws;
  size_t off = 0;
  auto alloc = [&](size_t bytes) { void* p = w + off; off = (off + bytes + 511) & ~(size_t)511; return p; };
  ushort* B1   = (ushort*)alloc((size_t)NV * 256 * 2);  // xl (bf16)
  ushort* B2   = (ushort*)alloc((size_t)NV * 256 * 2);  // xr (bf16)
  float*  B3   = (float*)alloc((size_t)NV * 256 * 4);   // res (f32)
  ushort* h0bf = (ushort*)alloc((size_t)NV * 64 * 2);
  ushort* h1bf = (ushort*)alloc((size_t)NV * 256 * 2);
  ushort* h2bf = (ushort*)alloc((size_t)NV * 256 * 2);
  ushort* Wcat[3];
  for (int i = 0; i < 3; ++i)
    Wcat[i] = (ushort*)alloc((size_t)(2 * hc[i] + oc[i]) * ic[i] * 2);
  float*    easumA  = (float*)alloc(3 * 64);
  int*      countsA = (int*)alloc((size_t)3 * (NV + 1) * 4);
  int*      cursorA = (int*)alloc((size_t)3 * NV * 4);
  unsigned* csrA    = (unsigned*)alloc((size_t)3 * CSRN * 4);
  ushort*   eabA    = (ushort*)alloc((size_t)3 * CSRN * 16 * 2);
  int*      bar     = (int*)alloc(128);

  // ---- node 1: merged preprocessing (zero+prep+scan+scatter, 3 grid barriers) ----
  PrepArgs pa;
  pa.x = in(0); pa.Wp = in(7); pa.bp = in(8); pa.gp = in(9); pa.bep = in(10);
  for (int i = 0; i < 3; ++i) {
    pa.ei[i] = (const int*)d_in[1 + 2 * i];
    pa.ea[i] = in(2 + 2 * i);
    pa.jobs[i * 3 + 0] = {in(11 + 11 * i), Wcat[i],                             ic[i], hc[i]};
    pa.jobs[i * 3 + 1] = {in(13 + 11 * i), Wcat[i] + (size_t)hc[i] * ic[i],     ic[i], hc[i]};
    pa.jobs[i * 3 + 2] = {in(20 + 11 * i), Wcat[i] + (size_t)2 * hc[i] * ic[i], ic[i], oc[i]};
    pa.csr[i] = csrA + (size_t)i * CSRN;
    pa.eab[i] = eabA + (size_t)i * CSRN * 16;
  }
  pa.h0 = h0bf; pa.easum = easumA; pa.counts = countsA; pa.cursor = cursorA;
  pa.bar = bar;
  prepcsr_kernel<<<GRID1, 256, 0, stream>>>(pa);

  // ---- nodes 2..7: per-layer fused GEMM + fused aggregate ----
  const ushort* hin[3] = {h0bf, h1bf, h2bf};
  ushort* hout_bf[3] = {h1bf, h2bf, nullptr};
  for (int i = 0; i < 3; ++i) {
    int K = ic[i], HCm = hc[i], OC = oc[i];
    int Mtot = 2 * HCm + OC;
    gemm_fused<<<dim3(Mtot / 64, (NV + 127) / 128), 256, 0, stream>>>(
        hin[i], Wcat[i], in(12 + 11 * i), in(14 + 11 * i), in(21 + 11 * i),
        B1, B2, B3, NV, K, HCm, 2 * HCm, Mtot);
    const int* offs = countsA + i * (NV + 1);
    const unsigned* csr = csrA + (size_t)i * CSRN;
    const ushort* eab = eabA + (size_t)i * CSRN * 16;
    const float* easum = easumA + i * 16;
    if (i < 2) {
      fused_agg_kernel<4><<<NV, 256, 0, stream>>>(
          eab, easum, in(15 + 11 * i), B1, B2, in(16 + 11 * i),
          in(17 + 11 * i), in(18 + 11 * i), in(19 + 11 * i), B3,
          offs, csr, nullptr, hout_bf[i], NE);
    } else {
      fused_agg_kernel<1><<<(NV + 3) / 4, 256, 0, stream>>>(
          eab, easum, in(15 + 11 * i), B1, B2, in(16 + 11 * i),
          in(17 + 11 * i), in(18 + 11 * i), in(19 + 11 * i), B3,
          offs, csr, (float*)d_out, nullptr, NE);
    }
  }
}

// Round 14
// 538.717 us; speedup vs baseline: 3.2670x; 1.5500x over previous
//
#include <hip/hip_runtime.h>
#include <hip/hip_bf16.h>
#include <math.h>

#define NV 20000
#define NE 320000
#define CSR_PAD 8

typedef __attribute__((ext_vector_type(8))) short bf16x8;
typedef __attribute__((ext_vector_type(4))) float f32x4;
typedef __attribute__((ext_vector_type(2))) _Float16 h2;

static __device__ __forceinline__ ushort f2b(float f) {
  __hip_bfloat16 h = __float2bfloat16(f);
  return *reinterpret_cast<ushort*>(&h);
}
static __device__ __forceinline__ float b2f(ushort u) {
  union { ushort s[2]; float f; } c;
  c.s[0] = 0; c.s[1] = u;
  return c.f;
}
static __device__ __forceinline__ ushort f2h(float f) {
  _Float16 h = (_Float16)f;
  return *reinterpret_cast<ushort*>(&h);
}
static __device__ __forceinline__ float blo(unsigned u) { return __uint_as_float(u << 16); }
static __device__ __forceinline__ float bhi(unsigned u) { return __uint_as_float(u & 0xffff0000u); }

// DPP wave-64 sum: lane 63 holds total, broadcast via readlane.
static __device__ __forceinline__ float wave_sum64(float x) {
  x += __int_as_float(__builtin_amdgcn_update_dpp(0, __float_as_int(x), 0x111, 0xF, 0xF, true));
  x += __int_as_float(__builtin_amdgcn_update_dpp(0, __float_as_int(x), 0x112, 0xF, 0xF, true));
  x += __int_as_float(__builtin_amdgcn_update_dpp(0, __float_as_int(x), 0x114, 0xF, 0xF, true));
  x += __int_as_float(__builtin_amdgcn_update_dpp(0, __float_as_int(x), 0x118, 0xF, 0xF, true));
  x += __int_as_float(__builtin_amdgcn_update_dpp(0, __float_as_int(x), 0x142, 0xA, 0xF, true));
  x += __int_as_float(__builtin_amdgcn_update_dpp(0, __float_as_int(x), 0x143, 0xC, 0xF, true));
  return __int_as_float(__builtin_amdgcn_readlane(__float_as_int(x), 63));
}

// 16-lane (DPP row) allreduce via rotations 1,2,4,8: every lane gets its row's sum.
static __device__ __forceinline__ float sum16(float x) {
  x += __int_as_float(__builtin_amdgcn_update_dpp(0, __float_as_int(x), 0x121, 0xF, 0xF, true));
  x += __int_as_float(__builtin_amdgcn_update_dpp(0, __float_as_int(x), 0x122, 0xF, 0xF, true));
  x += __int_as_float(__builtin_amdgcn_update_dpp(0, __float_as_int(x), 0x124, 0xF, 0xF, true));
  x += __int_as_float(__builtin_amdgcn_update_dpp(0, __float_as_int(x), 0x128, 0xF, 0xF, true));
  return x;
}

// 16-channel dot: edge attrs as 8 packed f16 pairs vs pre-packed We pairs.
static __device__ __forceinline__ float dot16h(const uint4* __restrict__ E,
                                               const h2* __restrict__ Wch) {
#if __has_builtin(__builtin_amdgcn_fdot2)
  const h2* e = (const h2*)E;
  float s = 0.f;
#pragma unroll
  for (int j = 0; j < 8; ++j) s = __builtin_amdgcn_fdot2(e[j], Wch[j], s, false);
  return s;
#else
  const unsigned* u = (const unsigned*)E;
  float s = 0.f;
#pragma unroll
  for (int j = 0; j < 8; ++j) {
    union { unsigned v; h2 h; } cv; cv.v = u[j];
    s = fmaf((float)cv.h[0], (float)Wch[j][0], s);
    s = fmaf((float)cv.h[1], (float)Wch[j][1], s);
  }
  return s;
#endif
}

// ---------------- batched prep: CSR hist + ea colsum (y<3), W casts (y==3), proj (y==4) ----------------
struct CJob { const float* src; ushort* dst; int K, M; };
struct PrepArgs {
  const int* ei[3];
  const float* ea[3];
  int* counts[3];
  float* easum[3];
  CJob jobs[9];
  const float *x, *Wp, *bp, *gp, *bep;
  ushort* h0;
};

__global__ __launch_bounds__(256) void prep_kernel(PrepArgs a) {
  const int y = blockIdx.y, t = threadIdx.x;
  if (y < 3) {
    if (blockIdx.x < 256) {
      const float4* ea4 = (const float4*)a.ea[y];
      const int cg = t & 3;
      int r = blockIdx.x * 64 + (t >> 2);
      const int rstride = 256 * 64;
      float4 s = make_float4(0.f, 0.f, 0.f, 0.f);
      for (; r < NE; r += rstride) {
        float4 v = ea4[(size_t)r * 4 + cg];
        s.x += v.x; s.y += v.y; s.z += v.z; s.w += v.w;
      }
      __shared__ float4 red4[256];
      red4[t] = s;
      __syncthreads();
      if (t < 4) {
        float4 tot = make_float4(0.f, 0.f, 0.f, 0.f);
        for (int j = t; j < 256; j += 4) {
          float4 v = red4[j];
          tot.x += v.x; tot.y += v.y; tot.z += v.z; tot.w += v.w;
        }
        atomicAdd(&a.easum[y][t * 4 + 0], tot.x);
        atomicAdd(&a.easum[y][t * 4 + 1], tot.y);
        atomicAdd(&a.easum[y][t * 4 + 2], tot.z);
        atomicAdd(&a.easum[y][t * 4 + 3], tot.w);
      }
    }
    int i = blockIdx.x * 256 + t;
    if (i < NE) atomicAdd(&a.counts[y][a.ei[y][NE + i]], 1);
  } else if (y == 3) {
#pragma unroll
    for (int j = 0; j < 9; ++j) {
      CJob jb = a.jobs[j];
      const int total = jb.M * jb.K;
      for (int i = blockIdx.x * 256 + t; i < total; i += gridDim.x * 256) {
        int m = i / jb.K, k = i - m * jb.K;
        jb.dst[i] = f2b(jb.src[(size_t)k * jb.M + m]);
      }
    }
  } else {
    int wid = t >> 6, lane = t & 63;
    for (int row = blockIdx.x * 4 + wid; row < NV; row += gridDim.x * 4) {
      float xv = a.x[(size_t)row * 64 + lane];
      float acc = a.bp[lane];
#pragma unroll
      for (int k = 0; k < 64; ++k) {
        float v = __shfl(xv, k, 64);
        acc = fmaf(v, a.Wp[k * 64 + lane], acc);
      }
      float s1 = wave_sum64(acc), s2 = wave_sum64(acc * acc);
      float mean = s1 * (1.0f / 64.0f);
      float var  = s2 * (1.0f / 64.0f) - mean * mean;
      float yv = (acc - mean) * rsqrtf(var + 1e-5f) * a.gp[lane] + a.bep[lane];
      float gel = 0.5f * yv * (1.0f + erff(yv * 0.70710678118654752f));
      a.h0[(size_t)row * 64 + lane] = f2b(gel);
    }
  }
}

// ---------------- batched scan: blockIdx.x = layer ----------------
__global__ __launch_bounds__(1024) void scan_kernel(
    int* __restrict__ countsA, int* __restrict__ cursorA)
{
  int* counts = countsA + blockIdx.x * (NV + 1);
  int* cursor = cursorA + blockIdx.x * NV;
  __shared__ int ws[16];
  __shared__ int wexcl[17];
  const int t = threadIdx.x, lane = t & 63, wid = t >> 6;
  const int base = t * 20;
  int v[20];
  int tot = 0;
#pragma unroll
  for (int j = 0; j < 20; ++j) {
    int i = base + j;
    v[j] = (i < NV) ? counts[i] : 0;
    tot += v[j];
  }
  int x = tot;
#pragma unroll
  for (int o = 1; o < 64; o <<= 1) {
    int yy = __shfl_up(x, o, 64);
    if (lane >= o) x += yy;
  }
  if (lane == 63) ws[wid] = x;
  __syncthreads();
  if (t == 0) {
    int r = 0;
#pragma unroll
    for (int j = 0; j < 16; ++j) { wexcl[j] = r; r += ws[j]; }
    wexcl[16] = r;
  }
  __syncthreads();
  int run = wexcl[wid] + (x - tot);
#pragma unroll
  for (int j = 0; j < 20; ++j) {
    int i = base + j;
    if (i < NV) { counts[i] = run; cursor[i] = run; }
    run += v[j];
  }
  if (t == 0) counts[NV] = wexcl[16];
}

// ---------------- merged: layer-0 GEMM tiles + all-layer scatter (independent work, one node) ----------------
struct G0SArgs {
  const ushort *A, *WT;
  const float *b0, *b1, *b2;
  ushort *O0, *O1; float* O2;
  int K, M1, M2, Mtot, NT;
  const int* ei[3]; const float* ea[3];
  int* cursor;
  unsigned* csr[3]; ushort* eab[3]; int HC[3];
};

__global__ __launch_bounds__(256) void gemm0_scatter_kernel(G0SArgs a) {
  __shared__ ushort As[128][40];
  __shared__ ushort Bs[64][40];
  const int t = threadIdx.x;
  if ((int)blockIdx.x < a.NT) {
    const int wave = t >> 6, lane = t & 63;
    const int mcols = a.Mtot >> 6;
    const int col0 = ((int)blockIdx.x % mcols) * 64, row0 = ((int)blockIdx.x / mcols) * 128;
    const int m_ = lane & 15, q = lane >> 4;
    f32x4 acc[2][4];
#pragma unroll
    for (int i = 0; i < 2; ++i)
#pragma unroll
      for (int j = 0; j < 4; ++j) acc[i][j] = (f32x4){0.f, 0.f, 0.f, 0.f};
    const int ar = t >> 1, ac = (t & 1) * 16;
    const int br = t >> 2, bcol = (t & 3) * 8;
    const ushort* Ap = a.A + (size_t)(row0 + ar) * a.K + ac;
    const ushort* Bp = a.WT + (size_t)(col0 + br) * a.K + bcol;
    const bool a_ok = (row0 + ar) < NV;
    for (int k0 = 0; k0 < a.K; k0 += 32) {
      uint4 av0 = make_uint4(0, 0, 0, 0), av1 = make_uint4(0, 0, 0, 0);
      if (a_ok) { av0 = *(const uint4*)(Ap + k0); av1 = *(const uint4*)(Ap + k0 + 8); }
      uint4 bv = *(const uint4*)(Bp + k0);
      *(uint4*)&As[ar][ac] = av0;
      *(uint4*)&As[ar][ac + 8] = av1;
      *(uint4*)&Bs[br][bcol] = bv;
      __syncthreads();
      bf16x8 a0 = *(const bf16x8*)&As[wave * 32 + m_][q * 8];
      bf16x8 a1 = *(const bf16x8*)&As[wave * 32 + 16 + m_][q * 8];
#pragma unroll
      for (int cf = 0; cf < 4; ++cf) {
        bf16x8 b = *(const bf16x8*)&Bs[cf * 16 + m_][q * 8];
        acc[0][cf] = __builtin_amdgcn_mfma_f32_16x16x32_bf16(a0, b, acc[0][cf], 0, 0, 0);
        acc[1][cf] = __builtin_amdgcn_mfma_f32_16x16x32_bf16(a1, b, acc[1][cf], 0, 0, 0);
      }
      __syncthreads();
    }
    const float* bias; int base, mode, Wd;
    if (col0 < a.M1)      { bias = a.b0; base = 0;    mode = 0; Wd = a.M1; }
    else if (col0 < a.M2) { bias = a.b1; base = a.M1; mode = 1; Wd = a.M2 - a.M1; }
    else                  { bias = a.b2; base = a.M2; mode = 2; Wd = a.Mtot - a.M2; }
#pragma unroll
    for (int rf = 0; rf < 2; ++rf) {
#pragma unroll
      for (int cf = 0; cf < 4; ++cf) {
        int col = col0 + cf * 16 + m_ - base;
        float bb = bias[col];
#pragma unroll
        for (int r = 0; r < 4; ++r) {
          int row = row0 + wave * 32 + rf * 16 + q * 4 + r;
          if (row < NV) {
            float v = acc[rf][cf][r] + bb;
            if (mode == 0)      a.O0[(size_t)row * Wd + col] = f2b(v);
            else if (mode == 1) a.O1[(size_t)row * Wd + col] = f2b(v);
            else                a.O2[(size_t)row * Wd + col] = v;
          }
        }
      }
    }
  } else {
    const int per = NE + CSR_PAD;
    int gi = ((int)blockIdx.x - a.NT) * 256 + t;
    if (gi >= 3 * per) return;
    int l = gi / per, i = gi - l * per;
    if (i >= NE) {
      a.csr[l][i] = 0u;
      uint4 z = make_uint4(0, 0, 0, 0);
      *(uint4*)(a.eab[l] + (size_t)i * 16) = z;
      *(uint4*)(a.eab[l] + (size_t)i * 16 + 8) = z;
      return;
    }
    int dst = a.ei[l][NE + i], src = a.ei[l][i];
    int pos = atomicAdd(&a.cursor[(size_t)l * NV + dst], 1);
    a.csr[l][pos] = (unsigned)(src * a.HC[l]);
    const float4* er = (const float4*)(a.ea[l] + (size_t)i * 16);
    float4 q0 = er[0], q1 = er[1], q2 = er[2], q3 = er[3];
    uint4 w0, w1;
    w0.x = (unsigned)f2h(q0.x) | ((unsigned)f2h(q0.y) << 16);
    w0.y = (unsigned)f2h(q0.z) | ((unsigned)f2h(q0.w) << 16);
    w0.z = (unsigned)f2h(q1.x) | ((unsigned)f2h(q1.y) << 16);
    w0.w = (unsigned)f2h(q1.z) | ((unsigned)f2h(q1.w) << 16);
    w1.x = (unsigned)f2h(q2.x) | ((unsigned)f2h(q2.y) << 16);
    w1.y = (unsigned)f2h(q2.z) | ((unsigned)f2h(q2.w) << 16);
    w1.z = (unsigned)f2h(q3.x) | ((unsigned)f2h(q3.y) << 16);
    w1.w = (unsigned)f2h(q3.z) | ((unsigned)f2h(q3.w) << 16);
    *(uint4*)(a.eab[l] + (size_t)pos * 16) = w0;
    *(uint4*)(a.eab[l] + (size_t)pos * 16 + 8) = w1;
  }
}

// ---------------- standalone GEMM for layers 1,2 ----------------
__global__ __launch_bounds__(256) void gemm_fused(
    const ushort* __restrict__ A, const ushort* __restrict__ WT,
    const float* __restrict__ b0, const float* __restrict__ b1,
    const float* __restrict__ b2,
    ushort* __restrict__ O0, ushort* __restrict__ O1, float* __restrict__ O2,
    int N, int K, int M1, int M2, int Mtot)
{
  __shared__ ushort As[128][40];
  __shared__ ushort Bs[64][40];
  const int t = threadIdx.x, wave = t >> 6, lane = t & 63;
  const int row0 = blockIdx.y * 128, col0 = blockIdx.x * 64;
  const int m_ = lane & 15, q = lane >> 4;
  f32x4 acc[2][4];
#pragma unroll
  for (int i = 0; i < 2; ++i)
#pragma unroll
    for (int j = 0; j < 4; ++j) acc[i][j] = (f32x4){0.f, 0.f, 0.f, 0.f};
  const int ar = t >> 1, ac = (t & 1) * 16;
  const int br = t >> 2, bcol = (t & 3) * 8;
  const ushort* Ap = A + (size_t)(row0 + ar) * K + ac;
  const ushort* Bp = WT + (size_t)(col0 + br) * K + bcol;
  const bool a_ok = (row0 + ar) < N;
  for (int k0 = 0; k0 < K; k0 += 32) {
    uint4 av0 = make_uint4(0, 0, 0, 0), av1 = make_uint4(0, 0, 0, 0);
    if (a_ok) { av0 = *(const uint4*)(Ap + k0); av1 = *(const uint4*)(Ap + k0 + 8); }
    uint4 bv = *(const uint4*)(Bp + k0);
    *(uint4*)&As[ar][ac] = av0;
    *(uint4*)&As[ar][ac + 8] = av1;
    *(uint4*)&Bs[br][bcol] = bv;
    __syncthreads();
    bf16x8 a0 = *(const bf16x8*)&As[wave * 32 + m_][q * 8];
    bf16x8 a1 = *(const bf16x8*)&As[wave * 32 + 16 + m_][q * 8];
#pragma unroll
    for (int cf = 0; cf < 4; ++cf) {
      bf16x8 b = *(const bf16x8*)&Bs[cf * 16 + m_][q * 8];
      acc[0][cf] = __builtin_amdgcn_mfma_f32_16x16x32_bf16(a0, b, acc[0][cf], 0, 0, 0);
      acc[1][cf] = __builtin_amdgcn_mfma_f32_16x16x32_bf16(a1, b, acc[1][cf], 0, 0, 0);
    }
    __syncthreads();
  }
  const float* bias; int base, mode, Wd;
  if (col0 < M1)      { bias = b0; base = 0;  mode = 0; Wd = M1; }
  else if (col0 < M2) { bias = b1; base = M1; mode = 1; Wd = M2 - M1; }
  else                { bias = b2; base = M2; mode = 2; Wd = Mtot - M2; }
#pragma unroll
  for (int rf = 0; rf < 2; ++rf) {
#pragma unroll
    for (int cf = 0; cf < 4; ++cf) {
      int col = col0 + cf * 16 + m_ - base;
      float bb = bias[col];
#pragma unroll
      for (int r = 0; r < 4; ++r) {
        int row = row0 + wave * 32 + rf * 16 + q * 4 + r;
        if (row < N) {
          float v = acc[rf][cf][r] + bb;
          if (mode == 0)      O0[(size_t)row * Wd + col] = f2b(v);
          else if (mode == 1) O1[(size_t)row * Wd + col] = f2b(v);
          else                O2[(size_t)row * Wd + col] = v;
        }
      }
    }
  }
}

// ---------------- H=4 agg: ONE WAVE PER NODE, 4 channels/lane ----------------
// lane l holds channels 4l..4l+3; head h = lanes [16h,16h+16) -> per-head score via
// sum16 (DPP row_ror allreduce). Uniform loads (csr + eab) issued ONCE per edge
// (vs 4x in the block-per-node layout); xl gather is one coalesced 8B load/lane.
__global__ __launch_bounds__(256) void agg4_kernel(
    const ushort* __restrict__ eab, const float* __restrict__ easum,
    const float* __restrict__ We,
    const ushort* __restrict__ xl, const ushort* __restrict__ xr,
    const float* __restrict__ att, const float* __restrict__ bc,
    const float* __restrict__ g, const float* __restrict__ be,
    const float* __restrict__ res,
    const int* __restrict__ offs, const unsigned* __restrict__ csr,
    ushort* __restrict__ houtb, int E)
{
  const int t = threadIdx.x, lane = t & 63, wave = t >> 6;
  const int n = blockIdx.x * 4 + wave;          // NV divisible by 4
  const int cb = 4 * lane;                      // channel base for this lane
  const size_t rowb = (size_t)n * 256 + cb;
  const float L2E = 1.4426950408889634f;

  float4 atv = *(const float4*)(att + cb);
  float at[4] = {atv.x * L2E, atv.y * L2E, atv.z * L2E, atv.w * L2E};

  h2 Wch[4][8];
  float esf[4] = {0.f, 0.f, 0.f, 0.f};
#pragma unroll
  for (int k = 0; k < 8; ++k) {
    float4 wr0 = *(const float4*)(We + (2 * k) * 256 + cb);
    float4 wr1 = *(const float4*)(We + (2 * k + 1) * 256 + cb);
    const float* w0 = &wr0.x;
    const float* w1 = &wr1.x;
    float e0 = easum[2 * k], e1 = easum[2 * k + 1];
#pragma unroll
    for (int j = 0; j < 4; ++j) {
      esf[j] = fmaf(e0, w0[j], esf[j]);
      esf[j] = fmaf(e1, w1[j], esf[j]);
      Wch[j][k] = (h2){(_Float16)w0[j], (_Float16)w1[j]};
    }
  }
#pragma unroll
  for (int j = 0; j < 4; ++j) esf[j] *= 1.0f / (float)E;

  uint2 qr = *(const uint2*)(xr + rowb);
  float xrv[4] = {blo(qr.x), bhi(qr.x), blo(qr.y), bhi(qr.y)};
  uint2 qn = *(const uint2*)(xl + rowb);
  float xln[4] = {blo(qn.x), bhi(qn.x), blo(qn.y), bhi(qn.y)};

  // self loop (analytic)
  float p = 0.f;
#pragma unroll
  for (int j = 0; j < 4; ++j) {
    float v = xln[j] + xrv[j] + esf[j];
    v = v > 0.f ? v : 0.2f * v;
    p = fmaf(v, at[j], p);
  }
  float wself = exp2f(sum16(p));
  float acc[4];
#pragma unroll
  for (int j = 0; j < 4; ++j) acc[j] = wself * xln[j];
  float denom = wself;

  const int beg = __builtin_amdgcn_readfirstlane(offs[n]);
  const int end = __builtin_amdgcn_readfirstlane(offs[n + 1]);

  unsigned P[2];
  uint4 EA[2][2];
  uint2 XL[2];
#pragma unroll
  for (int k = 0; k < 2; ++k) {
    P[k] = csr[beg + k];
    const uint4* ep = (const uint4*)(eab + (size_t)(beg + k) * 16);
    EA[k][0] = ep[0]; EA[k][1] = ep[1];
  }
#pragma unroll
  for (int k = 0; k < 2; ++k)
    XL[k] = *(const uint2*)(xl + __builtin_amdgcn_readfirstlane(P[k]) + cb);

  for (int idx = beg; idx < end; idx += 2) {
    unsigned Q[2];
    uint4 EB[2][2];
    uint2 XN[2];
#pragma unroll
    for (int k = 0; k < 2; ++k) Q[k] = csr[idx + 2 + k];
#pragma unroll
    for (int k = 0; k < 2; ++k) {
      const uint4* ep = (const uint4*)(eab + (size_t)(idx + 2 + k) * 16);
      EB[k][0] = ep[0]; EB[k][1] = ep[1];
    }
#pragma unroll
    for (int k = 0; k < 2; ++k)
      XN[k] = *(const uint2*)(xl + __builtin_amdgcn_readfirstlane(Q[k]) + cb);

#pragma unroll
    for (int k = 0; k < 2; ++k) {
      float xf[4] = {blo(XL[k].x), bhi(XL[k].x), blo(XL[k].y), bhi(XL[k].y)};
      float pp = 0.f;
#pragma unroll
      for (int j = 0; j < 4; ++j) {
        float ee = dot16h(EA[k], Wch[j]);
        float v = xf[j] + xrv[j] + ee;
        v = v > 0.f ? v : 0.2f * v;  // leaky_relu(0.2)
        pp = fmaf(v, at[j], pp);
      }
      float S = sum16(pp);
      float w = (idx + k < end) ? exp2f(S) : 0.f;
#pragma unroll
      for (int j = 0; j < 4; ++j) acc[j] = fmaf(w, xf[j], acc[j]);
      denom += w;
    }
#pragma unroll
    for (int k = 0; k < 2; ++k) { P[k] = Q[k]; EA[k][0] = EB[k][0]; EA[k][1] = EB[k][1]; XL[k] = XN[k]; }
  }

  const float inv = 1.0f / (denom + 1e-16f);
  float4 bcv = *(const float4*)(bc + cb);
  float out[4];
  out[0] = acc[0] * inv + bcv.x; out[1] = acc[1] * inv + bcv.y;
  out[2] = acc[2] * inv + bcv.z; out[3] = acc[3] * inv + bcv.w;

  // LayerNorm over 256 channels: full-wave sums of per-lane partials
  float so1 = out[0] + out[1] + out[2] + out[3];
  float so2 = out[0] * out[0] + out[1] * out[1] + out[2] * out[2] + out[3] * out[3];
  float s1 = wave_sum64(so1), s2 = wave_sum64(so2);
  float mean = s1 * (1.0f / 256.0f);
  float var  = s2 * (1.0f / 256.0f) - mean * mean;
  float rstd = rsqrtf(var + 1e-5f);
  float4 gv = *(const float4*)(g + cb);
  float4 bev = *(const float4*)(be + cb);
  float4 rv = *(const float4*)(res + rowb);
  const float* gp = &gv.x; const float* bep = &bev.x; const float* rp = &rv.x;
  ushort ob[4];
#pragma unroll
  for (int j = 0; j < 4; ++j) {
    float y = (out[j] - mean) * rstd * gp[j] + bep[j];
    float gel = 0.5f * y * (1.0f + erff(y * 0.70710678118654752f));
    ob[j] = f2b(gel + rp[j]);
  }
  uint2 ov;
  ov.x = (unsigned)ob[0] | ((unsigned)ob[1] << 16);
  ov.y = (unsigned)ob[2] | ((unsigned)ob[3] << 16);
  *(uint2*)(houtb + rowb) = ov;
}

// ---------------- H=1 agg (layer 2): one wave per node (r10 form) ----------------
__global__ __launch_bounds__(256, 4) void agg1_kernel(
    const ushort* __restrict__ eab, const float* __restrict__ easum,
    const float* __restrict__ We,
    const ushort* __restrict__ xl, const ushort* __restrict__ xr,
    const float* __restrict__ att, const float* __restrict__ bc,
    const float* __restrict__ g, const float* __restrict__ be,
    const float* __restrict__ res,
    const int* __restrict__ offs, const unsigned* __restrict__ csr,
    float* __restrict__ houtf, int E)
{
  const int HC = 64;
  const int t = threadIdx.x, lane = t & 63, wave = t >> 6;
  const int n = blockIdx.x * 4 + wave;
  const int c = lane;

  const float xr_t = b2f(xr[(size_t)n * HC + c]);
  const float att_t = att[c] * 1.4426950408889634f;
  float eself = 0.f;
  h2 Wch[8];
#pragma unroll
  for (int j = 0; j < 8; ++j) {
    float w0 = We[(2 * j) * HC + c], w1 = We[(2 * j + 1) * HC + c];
    eself = fmaf(easum[2 * j], w0, eself);
    eself = fmaf(easum[2 * j + 1], w1, eself);
    Wch[j] = (h2){(_Float16)w0, (_Float16)w1};
  }
  eself *= 1.0f / (float)E;

  const float xln = b2f(xl[(size_t)n * HC + c]);
  float vs = xln + xr_t + eself;
  vs = vs > 0.f ? vs : 0.2f * vs;
  const float wself = exp2f(wave_sum64(vs * att_t));
  float acc = wself * xln, denom = wself;

  const int beg = __builtin_amdgcn_readfirstlane(offs[n]);
  const int end = __builtin_amdgcn_readfirstlane(offs[n + 1]);

  unsigned P[4];
  uint4 EA[4][2];
  float XL[4];
#pragma unroll
  for (int k = 0; k < 4; ++k) {
    P[k] = csr[beg + k];
    const uint4* ep = (const uint4*)(eab + (size_t)(beg + k) * 16);
    EA[k][0] = ep[0]; EA[k][1] = ep[1];
  }
#pragma unroll
  for (int k = 0; k < 4; ++k)
    XL[k] = b2f(xl[__builtin_amdgcn_readfirstlane(P[k]) + c]);

  for (int idx = beg; idx < end; idx += 4) {
    unsigned Q[4];
    uint4 EB[4][2];
    float XLN[4];
#pragma unroll
    for (int k = 0; k < 4; ++k) Q[k] = csr[idx + 4 + k];
#pragma unroll
    for (int k = 0; k < 4; ++k) {
      const uint4* ep = (const uint4*)(eab + (size_t)(idx + 4 + k) * 16);
      EB[k][0] = ep[0]; EB[k][1] = ep[1];
    }
#pragma unroll
    for (int k = 0; k < 4; ++k)
      XLN[k] = b2f(xl[__builtin_amdgcn_readfirstlane(Q[k]) + c]);

    float wv[4];
#pragma unroll
    for (int k = 0; k < 4; ++k) {
      float ee = dot16h(EA[k], Wch);
      float v = XL[k] + xr_t + ee;
      v = v > 0.f ? v : 0.2f * v;
      float S = wave_sum64(v * att_t);
      wv[k] = (idx + k < end) ? exp2f(S) : 0.f;
    }
#pragma unroll
    for (int k = 0; k < 4; ++k) { acc = fmaf(wv[k], XL[k], acc); denom += wv[k]; }
#pragma unroll
    for (int k = 0; k < 4; ++k) {
      P[k] = Q[k]; EA[k][0] = EB[k][0]; EA[k][1] = EB[k][1]; XL[k] = XLN[k];
    }
  }

  float out = acc / (denom + 1e-16f) + bc[c];
  float s1 = wave_sum64(out), s2 = wave_sum64(out * out);
  float mean = s1 / (float)HC;
  float var  = s2 / (float)HC - mean * mean;
  float y = (out - mean) * rsqrtf(var + 1e-5f) * g[c] + be[c];
  float gel = 0.5f * y * (1.0f + erff(y * 0.70710678118654752f));
  houtf[(size_t)n * HC + c] = gel + res[(size_t)n * HC + c];
}

// ---------------- host launch ----------------
extern "C" void kernel_launch(void* const* d_in, const int* in_sizes, int n_in,
                              void* d_out, int out_size, void* d_ws, size_t ws_size,
                              hipStream_t stream)
{
  auto in = [&](int i) { return (const float*)d_in[i]; };
  // per-layer base 11 + 11*i: Wl, bl, Wr, br, We, att, bc, g, be, Wsk, bsk

  const int ic[3] = {64, 256, 256}, hc[3] = {256, 256, 64}, oc[3] = {256, 256, 64};
  const int CSRN = NE + CSR_PAD;

  // ---- workspace layout (~100 MB) ----
  char* w = (char*)d_ws;
  size_t off = 0;
  auto alloc = [&](size_t bytes) { void* p = w + off; off = (off + bytes + 511) & ~(size_t)511; return p; };
  ushort* B1   = (ushort*)alloc((size_t)NV * 256 * 2);  // xl (bf16)
  ushort* B2   = (ushort*)alloc((size_t)NV * 256 * 2);  // xr (bf16)
  float*  B3   = (float*)alloc((size_t)NV * 256 * 4);   // res (f32)
  ushort* h0bf = (ushort*)alloc((size_t)NV * 64 * 2);
  ushort* h1bf = (ushort*)alloc((size_t)NV * 256 * 2);
  ushort* h2bf = (ushort*)alloc((size_t)NV * 256 * 2);
  ushort* Wcat[3];
  for (int i = 0; i < 3; ++i)
    Wcat[i] = (ushort*)alloc((size_t)(2 * hc[i] + oc[i]) * ic[i] * 2);
  float*    easumA  = (float*)alloc(3 * 64);
  int*      countsA = (int*)alloc((size_t)3 * (NV + 1) * 4);
  int*      cursorA = (int*)alloc((size_t)3 * NV * 4);
  unsigned* csrA    = (unsigned*)alloc((size_t)3 * CSRN * 4);
  ushort*   eabA    = (ushort*)alloc((size_t)3 * CSRN * 16 * 2);

  // ---- node 1: zero easums + counts ----
  hipMemsetAsync(easumA, 0, 512 + (size_t)3 * (NV + 1) * 4, stream);

  // ---- node 2: batched prep ----
  PrepArgs pa;
  for (int i = 0; i < 3; ++i) {
    pa.ei[i] = (const int*)d_in[1 + 2 * i];
    pa.ea[i] = in(2 + 2 * i);
    pa.counts[i] = countsA + i * (NV + 1);
    pa.easum[i] = easumA + i * 16;
    pa.jobs[i * 3 + 0] = {in(11 + 11 * i), Wcat[i],                             ic[i], hc[i]};
    pa.jobs[i * 3 + 1] = {in(13 + 11 * i), Wcat[i] + (size_t)hc[i] * ic[i],     ic[i], hc[i]};
    pa.jobs[i * 3 + 2] = {in(20 + 11 * i), Wcat[i] + (size_t)2 * hc[i] * ic[i], ic[i], oc[i]};
  }
  pa.x = in(0); pa.Wp = in(7); pa.bp = in(8); pa.gp = in(9); pa.bep = in(10);
  pa.h0 = h0bf;
  prep_kernel<<<dim3(1344, 5), 256, 0, stream>>>(pa);

  // ---- node 3: scan ----
  scan_kernel<<<3, 1024, 0, stream>>>(countsA, cursorA);

  // ---- node 4: layer-0 GEMM + all-layer scatter (independent; merged) ----
  // BUGFIX r13: layer-0 oc=256 -> Mtot = 2*256+256 = 768 (r13 wrongly used 576,
  // truncating the skip projection to 64 cols with wrong stride -> absmax 1.41).
  G0SArgs ga;
  ga.A = h0bf; ga.WT = Wcat[0];
  ga.b0 = in(12); ga.b1 = in(14); ga.b2 = in(21);
  ga.O0 = B1; ga.O1 = B2; ga.O2 = B3;
  ga.K = 64; ga.M1 = 256; ga.M2 = 512; ga.Mtot = 768;
  ga.NT = (768 / 64) * ((NV + 127) / 128);  // 12 * 157 = 1884
  for (int i = 0; i < 3; ++i) {
    ga.ei[i] = (const int*)d_in[1 + 2 * i];
    ga.ea[i] = in(2 + 2 * i);
    ga.csr[i] = csrA + (size_t)i * CSRN;
    ga.eab[i] = eabA + (size_t)i * CSRN * 16;
    ga.HC[i] = hc[i];
  }
  ga.cursor = cursorA;
  const int scat_blocks = (3 * (NE + CSR_PAD) + 255) / 256;
  gemm0_scatter_kernel<<<ga.NT + scat_blocks, 256, 0, stream>>>(ga);

  // ---- node 5: agg layer 0 ----
  agg4_kernel<<<NV / 4, 256, 0, stream>>>(
      eabA + 0, easumA + 0, in(15), B1, B2, in(16), in(17), in(18), in(19),
      B3, countsA, csrA, h1bf, NE);

  // ---- node 6: gemm layer 1 ----
  gemm_fused<<<dim3(768 / 64, (NV + 127) / 128), 256, 0, stream>>>(
      h1bf, Wcat[1], in(23), in(25), in(32), B1, B2, B3, NV, 256, 256, 512, 768);

  // ---- node 7: agg layer 1 ----
  agg4_kernel<<<NV / 4, 256, 0, stream>>>(
      eabA + (size_t)CSRN * 16, easumA + 16, in(26), B1, B2, in(27), in(28),
      in(29), in(30), B3, countsA + (NV + 1), csrA + (size_t)CSRN, h2bf, NE);

  // ---- node 8: gemm layer 2 ----
  gemm_fused<<<dim3(192 / 64, (NV + 127) / 128), 256, 0, stream>>>(
      h2bf, Wcat[2], in(34), in(36), in(43), B1, B2, B3, NV, 256, 64, 128, 192);

  // ---- node 9: agg layer 2 -> d_out ----
  agg1_kernel<<<NV / 4, 256, 0, stream>>>(
      eabA + (size_t)2 * CSRN * 16, easumA + 32, in(37), B1, B2, in(38), in(39),
      in(40), in(41), B3, countsA + 2 * (NV + 1), csrA + (size_t)2 * CSRN,
      (float*)d_out, NE);
}